// Round 8
// baseline (682.370 us; speedup 1.0000x reference)
//
#include <hip/hip_runtime.h>

#define NN 100000
#define NE 800000
#define NBLK 196    // ceil(100000/512): scan blocks AND dst-buckets (512 nodes each)
#define BCAP 6144   // bucket capacity (mean 4096, sigma ~64 -> +32 sigma)

typedef unsigned short ushort_t;
typedef unsigned int uint_t;
typedef __attribute__((ext_vector_type(8))) short short8;
typedef __attribute__((ext_vector_type(4))) float floatx4;

__device__ __forceinline__ float bf2f(ushort_t u) {
    union { unsigned int i; float f; } v; v.i = ((unsigned int)u) << 16; return v.f;
}
__device__ __forceinline__ ushort_t f2bf(float f) {
    union { float f; unsigned int i; } v; v.f = f;
    unsigned int b = v.i + 0x7FFF + ((v.i >> 16) & 1);
    return (ushort_t)(b >> 16);
}
__device__ __forceinline__ uint_t pack2(float a, float b) {
    return (uint_t)f2bf(a) | ((uint_t)f2bf(b) << 16);
}

// ---------------- pass 1: partition edges into 196 dst-buckets ----------------
// record = src | (dstLocal<<17)   (src < 2^17, dstLocal < 512)
__global__ void k_part(const int* __restrict__ src, const int* __restrict__ dst,
                       int* __restrict__ bcnt, int* __restrict__ bedge) {
    int e = blockIdx.x * 256 + threadIdx.x;
    if (e < NE) {
        int s = src[e], d = dst[e];
        int b = d >> 9;
        int pos = atomicAdd(&bcnt[b], 1);
        bedge[b * BCAP + pos] = s | ((d & 511) << 17);
    }
}

// ---------------- per-bucket degree histogram -> deg, dis (coalesced) ----------------
__global__ __launch_bounds__(256) void k_bhist(const int* __restrict__ bcnt,
                                               const int* __restrict__ bedge,
                                               int* __restrict__ deg, float* __restrict__ dis) {
    __shared__ int hist[512];
    int b = blockIdx.x, t = threadIdx.x;
    hist[t] = 0; hist[t + 256] = 0;
    __syncthreads();
    int cnt = bcnt[b];
    const int* be = bedge + b * BCAP;
    for (int i = t; i < cnt; i += 256) {
        atomicAdd(&hist[be[i] >> 17], 1);
    }
    __syncthreads();
    #pragma unroll
    for (int q = 0; q < 2; ++q) {
        int j = t + q * 256;
        int gn = b * 512 + j;
        if (gn < NN) {
            int h = hist[j];
            deg[gn] = h;
            dis[gn] = rsqrtf((float)h + 1.0f);
        }
    }
}

// ---------------- 3-pass exclusive scan of deg -> off ----------------
__global__ __launch_bounds__(256) void k_scan1(const int* __restrict__ deg, int* __restrict__ bsum) {
    __shared__ int s[256];
    int b = blockIdx.x, t = threadIdx.x;
    int g0 = b * 512;
    int v = 0;
    int g1 = g0 + t, g2 = g0 + t + 256;
    if (g1 < NN) v += deg[g1];
    if (g2 < NN) v += deg[g2];
    s[t] = v;
    __syncthreads();
    for (int o = 128; o > 0; o >>= 1) {
        if (t < o) s[t] += s[t + o];
        __syncthreads();
    }
    if (t == 0) bsum[b] = s[0];
}

__global__ __launch_bounds__(256) void k_scan2(const int* __restrict__ bsum, int* __restrict__ base) {
    __shared__ int s[NBLK];
    int t = threadIdx.x;
    if (t < NBLK) s[t] = bsum[t];
    __syncthreads();
    if (t == 0) {
        int run = 0;
        for (int i = 0; i < NBLK; ++i) { int v = s[i]; s[i] = run; run += v; }
    }
    __syncthreads();
    if (t < NBLK) base[t] = s[t];
}

__global__ __launch_bounds__(256) void k_scan3(const int* __restrict__ deg, const int* __restrict__ base,
                                               int* __restrict__ off) {
    __shared__ int s[2][512];
    int b = blockIdx.x, t = threadIdx.x;
    int g0 = b * 512;
    #pragma unroll
    for (int q = 0; q < 2; ++q) {
        int j = t + q * 256, g = g0 + j;
        s[0][j] = (g < NN) ? deg[g] : 0;
    }
    __syncthreads();
    int c = 0;
    for (int o = 1; o < 512; o <<= 1) {
        int nxt = c ^ 1;
        #pragma unroll
        for (int q = 0; q < 2; ++q) {
            int j = t + q * 256;
            s[nxt][j] = s[c][j] + ((j >= o) ? s[c][j - o] : 0);
        }
        c = nxt;
        __syncthreads();
    }
    int bb = base[b];
    #pragma unroll
    for (int q = 0; q < 2; ++q) {
        int j = t + q * 256, g = g0 + j;
        if (g <= NN) off[g] = bb + ((j > 0) ? s[c][j - 1] : 0);
    }
}

// ---------------- per-bucket CSR place: LDS cursors, contiguous slot region ----------------
__global__ __launch_bounds__(256) void k_place(const int* __restrict__ bcnt,
                                               const int* __restrict__ bedge,
                                               const int* __restrict__ off,
                                               int* __restrict__ ssrc) {
    __shared__ int lcur[512];
    int b = blockIdx.x, t = threadIdx.x;
    #pragma unroll
    for (int q = 0; q < 2; ++q) {
        int j = t + q * 256;
        int gn = b * 512 + j;
        lcur[j] = (gn < NN) ? off[gn] : 0;
    }
    __syncthreads();
    int cnt = bcnt[b];
    const int* be = bedge + b * BCAP;
    for (int i = t; i < cnt; i += 256) {
        int v = be[i];
        int s = v & 0x1FFFF;
        int dl = v >> 17;
        int pos = atomicAdd(&lcur[dl], 1);
        ssrc[pos] = s;
    }
}

// ---------------- one-shot W^T pre-pack to global (bf16 pairs) ----------------
__global__ __launch_bounds__(64) void k_packW(
    const float* __restrict__ W1,
    const float* __restrict__ Wmu, const float* __restrict__ Wls,
    uint_t* __restrict__ Wt1g, uint_t* __restrict__ Wt2g)
{
    int b = blockIdx.x;
    int mat = b / 112, n = b - mat * 112;
    int kp = threadIdx.x;
    int k0 = kp * 2, k1 = k0 + 1;
    float w0 = 0.0f, w1 = 0.0f;
    if (mat == 0) {
        if (n < 100) {
            if (k0 < 100) w0 = W1[k0 * 100 + n];
            if (k1 < 100) w1 = W1[k1 * 100 + n];
        }
        Wt1g[n * 64 + kp] = pack2(w0, w1);
    } else {
        if (n < 50) {
            if (k0 < 100) w0 = Wmu[k0 * 50 + n];
            if (k1 < 100) w1 = Wmu[k1 * 50 + n];
        } else if (n < 100) {
            if (k0 < 100) w0 = Wls[k0 * 50 + (n - 50)];
            if (k1 < 100) w1 = Wls[k1 * 50 + (n - 50)];
        }
        Wt2g[n * 64 + kp] = pack2(w0, w1);
    }
}

// ---------------- MFMA GEMM 1: H1' = bf16((X @ W1) * dis), pads zeroed ----------------
__global__ __launch_bounds__(256) void k_gemm1_mfma(
    const float* __restrict__ X, const uint_t* __restrict__ Wtg,
    const float* __restrict__ dis,
    ushort_t* __restrict__ H)
{
    __shared__ ushort_t Ws[112 * 136];   // 30.5 KB
    const int tid = threadIdx.x;
    const int row0 = blockIdx.x * 64;

    for (int idx = tid; idx < 112 * 16; idx += 256) {
        int n = idx >> 4, c = idx & 15;
        uint4 v = *(const uint4*)&Wtg[n * 64 + c * 4];
        *(uint4*)&Ws[n * 136 + c * 8] = v;
    }
    __syncthreads();

    const int wave = tid >> 6, lane = tid & 63;
    const int quad = lane >> 4, l16 = lane & 15;
    int row = row0 + wave * 16 + l16;
    if (row >= NN) row = NN - 1;
    const float* xp = X + (size_t)row * 100;

    floatx4 acc[7];
    #pragma unroll
    for (int t = 0; t < 7; ++t) acc[t] = (floatx4){0.f, 0.f, 0.f, 0.f};

    #pragma unroll
    for (int ks = 0; ks < 4; ++ks) {
        const int kb = ks * 32 + quad * 8;
        short8 af;
        if (ks < 3) {
            float4 u = *(const float4*)&xp[kb];
            float4 v = *(const float4*)&xp[kb + 4];
            af[0] = (short)f2bf(u.x); af[1] = (short)f2bf(u.y);
            af[2] = (short)f2bf(u.z); af[3] = (short)f2bf(u.w);
            af[4] = (short)f2bf(v.x); af[5] = (short)f2bf(v.y);
            af[6] = (short)f2bf(v.z); af[7] = (short)f2bf(v.w);
        } else {
            af = (short8){0, 0, 0, 0, 0, 0, 0, 0};
            if (quad == 0) {
                float4 u = *(const float4*)&xp[96];
                af[0] = (short)f2bf(u.x); af[1] = (short)f2bf(u.y);
                af[2] = (short)f2bf(u.z); af[3] = (short)f2bf(u.w);
            }
        }
        #pragma unroll
        for (int t = 0; t < 7; ++t) {
            short8 bf = *(const short8*)&Ws[(t * 16 + l16) * 136 + kb];
            acc[t] = __builtin_amdgcn_mfma_f32_16x16x32_bf16(af, bf, acc[t], 0, 0, 0);
        }
    }

    const int mbase = row0 + wave * 16 + quad * 4;
    #pragma unroll
    for (int reg = 0; reg < 4; ++reg) {
        int m = mbase + reg;
        if (m >= NN) continue;
        float dd = dis[m];
        #pragma unroll
        for (int t = 0; t < 7; ++t) {
            int n = t * 16 + l16;
            H[(size_t)m * 128 + n] = (n < 100) ? f2bf(acc[t][reg] * dd) : (ushort_t)0;
        }
        H[(size_t)m * 128 + 112 + l16] = 0;
    }
}

// ---------------- MFMA GEMM 2: out = A2 @ [Wmu|Wls] + [bmu|bls] ----------------
__global__ __launch_bounds__(256) void k_gemm2_mfma(
    const ushort_t* __restrict__ A,   // bf16, stride 128, k-padded w/ zeros
    const uint_t* __restrict__ Wtg,
    const float* __restrict__ bmu, const float* __restrict__ bls,
    float* __restrict__ outmu, float* __restrict__ outls)
{
    __shared__ ushort_t Ws[112 * 136];
    const int tid = threadIdx.x;
    const int row0 = blockIdx.x * 64;

    for (int idx = tid; idx < 112 * 16; idx += 256) {
        int n = idx >> 4, c = idx & 15;
        uint4 v = *(const uint4*)&Wtg[n * 64 + c * 4];
        *(uint4*)&Ws[n * 136 + c * 8] = v;
    }
    __syncthreads();

    const int wave = tid >> 6, lane = tid & 63;
    const int quad = lane >> 4, l16 = lane & 15;
    int arow = row0 + wave * 16 + l16;
    if (arow >= NN) arow = NN - 1;

    floatx4 acc[7];
    #pragma unroll
    for (int t = 0; t < 7; ++t) acc[t] = (floatx4){0.f, 0.f, 0.f, 0.f};

    #pragma unroll
    for (int k0 = 0; k0 < 128; k0 += 32) {
        short8 af = *(const short8*)&A[(size_t)arow * 128 + k0 + quad * 8];
        #pragma unroll
        for (int t = 0; t < 7; ++t) {
            short8 bf = *(const short8*)&Ws[(t * 16 + l16) * 136 + k0 + quad * 8];
            acc[t] = __builtin_amdgcn_mfma_f32_16x16x32_bf16(af, bf, acc[t], 0, 0, 0);
        }
    }

    const int mbase = row0 + wave * 16 + quad * 4;
    #pragma unroll
    for (int reg = 0; reg < 4; ++reg) {
        int m = mbase + reg;
        if (m >= NN) continue;
        #pragma unroll
        for (int t = 0; t < 7; ++t) {
            int n = t * 16 + l16;
            if (n < 50) {
                outmu[(size_t)m * 50 + n] = acc[t][reg] + bmu[n];
            } else if (n < 100) {
                outls[(size_t)m * 50 + (n - 50)] = acc[t][reg] + bls[n - 50];
            }
        }
    }
}

// ---------------- aggregation (gather, scale-folded, src-only CSR) ----------------
// in: H' rows (feat * dis[row]), stride 128, pads zero.
// val = dis[node] * (H'[node] + sum_e H'[src])
// PHASE 1: store bf16(relu(val + b1) * dis[node])   PHASE 2: store bf16(val)
template<int PHASE>
__global__ __launch_bounds__(256) void k_agg(
    const ushort_t* __restrict__ Hin,
    const int* __restrict__ off, const int* __restrict__ ssrc,
    const float* __restrict__ dis, const float* __restrict__ bias,
    ushort_t* __restrict__ outb)
{
    int i = blockIdx.x * 256 + threadIdx.x;
    if (i >= NN * 8) return;
    int node = i >> 3;
    int col = (i & 7) * 16;

    float a[16];
    {
        short8 u = *(const short8*)(Hin + (size_t)node * 128 + col);
        short8 v = *(const short8*)(Hin + (size_t)node * 128 + col + 8);
        #pragma unroll
        for (int j = 0; j < 8; ++j) { a[j] = bf2f((ushort_t)u[j]); a[8 + j] = bf2f((ushort_t)v[j]); }
    }

    int e0 = off[node], e1 = off[node + 1];
    int e = e0;
    for (; e + 3 < e1; e += 4) {
        int s0 = ssrc[e], s1 = ssrc[e + 1], s2 = ssrc[e + 2], s3 = ssrc[e + 3];
        short8 u0 = *(const short8*)(Hin + (size_t)s0 * 128 + col);
        short8 v0 = *(const short8*)(Hin + (size_t)s0 * 128 + col + 8);
        short8 u1 = *(const short8*)(Hin + (size_t)s1 * 128 + col);
        short8 v1 = *(const short8*)(Hin + (size_t)s1 * 128 + col + 8);
        short8 u2 = *(const short8*)(Hin + (size_t)s2 * 128 + col);
        short8 v2 = *(const short8*)(Hin + (size_t)s2 * 128 + col + 8);
        short8 u3 = *(const short8*)(Hin + (size_t)s3 * 128 + col);
        short8 v3 = *(const short8*)(Hin + (size_t)s3 * 128 + col + 8);
        #pragma unroll
        for (int j = 0; j < 8; ++j) {
            a[j]     += bf2f((ushort_t)u0[j]) + bf2f((ushort_t)u1[j])
                      + bf2f((ushort_t)u2[j]) + bf2f((ushort_t)u3[j]);
            a[8 + j] += bf2f((ushort_t)v0[j]) + bf2f((ushort_t)v1[j])
                      + bf2f((ushort_t)v2[j]) + bf2f((ushort_t)v3[j]);
        }
    }
    for (; e < e1; ++e) {
        int s0 = ssrc[e];
        short8 u0 = *(const short8*)(Hin + (size_t)s0 * 128 + col);
        short8 v0 = *(const short8*)(Hin + (size_t)s0 * 128 + col + 8);
        #pragma unroll
        for (int j = 0; j < 8; ++j) {
            a[j] += bf2f((ushort_t)u0[j]);
            a[8 + j] += bf2f((ushort_t)v0[j]);
        }
    }

    float d = dis[node];
    short8 o0, o1;
    if (PHASE == 1) {
        float b[16];
        #pragma unroll
        for (int j = 0; j < 16; ++j) {
            int cj = col + j;
            b[j] = (cj < 100) ? bias[cj] : 0.0f;
        }
        #pragma unroll
        for (int j = 0; j < 8; ++j) {
            float h0 = fmaxf(a[j] * d + b[j], 0.0f) * d;
            float h1 = fmaxf(a[8 + j] * d + b[8 + j], 0.0f) * d;
            o0[j] = (short)f2bf(h0);
            o1[j] = (short)f2bf(h1);
        }
    } else {
        #pragma unroll
        for (int j = 0; j < 8; ++j) {
            o0[j] = (short)f2bf(a[j] * d);
            o1[j] = (short)f2bf(a[8 + j] * d);
        }
    }
    *(short8*)(outb + (size_t)node * 128 + col) = o0;
    *(short8*)(outb + (size_t)node * 128 + col + 8) = o1;
}

extern "C" void kernel_launch(void* const* d_in, const int* in_sizes, int n_in,
                              void* d_out, int out_size, void* d_ws, size_t ws_size,
                              hipStream_t stream)
{
    const float* x   = (const float*)d_in[0];
    const int*   ei  = (const int*)d_in[1];
    const float* W1  = (const float*)d_in[2];
    const float* b1  = (const float*)d_in[3];
    const float* Wmu = (const float*)d_in[4];
    const float* bmu = (const float*)d_in[5];
    const float* Wls = (const float*)d_in[6];
    const float* bls = (const float*)d_in[7];
    float* out = (float*)d_out;

    const int* src = ei;
    const int* dst = ei + NE;

    // workspace layout (4B element offsets)
    int*   wsI  = (int*)d_ws;
    float* wsF  = (float*)d_ws;
    int*      deg  = wsI;                         // 100000
    int*      off  = wsI + 100000;                // 100001 -> pad 200064
    int*      bsum = wsI + 200064;                // 256
    int*      base = wsI + 200384;                // 256
    float*    dis  = wsF + 200704;                // 100000
    uint_t*   Wt1g = (uint_t*)(wsI + 300704);     // 7168
    uint_t*   Wt2g = (uint_t*)(wsI + 307872);     // 7168 -> 315040
    int*      bcnt = wsI + 315040;                // 196 pad 256 -> 315296
    int*      ssrc = wsI + 315296;                // 800000 -> 1115296
    int*      bedge= wsI + 1115296;               // 196*6144 = 1204224 -> 2319520
    ushort_t* H1b  = (ushort_t*)(wsI + 2319520);  // 100000*128 bf16 -> 8719520
    ushort_t* hb   = (ushort_t*)(wsI + 8719520);  // -> 15119520
    ushort_t* A2b  = (ushort_t*)(wsI + 15119520); // -> 21519520

    hipMemsetAsync(bcnt, 0, 256 * sizeof(int), stream);
    k_part<<<(NE + 255) / 256, 256, 0, stream>>>(src, dst, bcnt, bedge);
    k_bhist<<<NBLK, 256, 0, stream>>>(bcnt, bedge, deg, dis);
    k_scan1<<<NBLK, 256, 0, stream>>>(deg, bsum);
    k_scan2<<<1, 256, 0, stream>>>(bsum, base);
    k_scan3<<<NBLK, 256, 0, stream>>>(deg, base, off);
    k_place<<<NBLK, 256, 0, stream>>>(bcnt, bedge, off, ssrc);
    k_packW<<<224, 64, 0, stream>>>(W1, Wmu, Wls, Wt1g, Wt2g);

    const int gblk = (NN + 63) / 64;
    // layer 1: H1' = bf16(X@W1 * dis) ; hb = bf16(relu(dis*(sum H1') + b1) * dis)
    k_gemm1_mfma<<<gblk, 256, 0, stream>>>(x, Wt1g, dis, H1b);
    k_agg<1><<<(NN * 8 + 255) / 256, 256, 0, stream>>>(H1b, off, ssrc, dis, b1, hb);
    // layer 2: A2 = bf16(dis*(sum hb)) ; out = A2@[Wmu|Wls] + bias
    k_agg<2><<<(NN * 8 + 255) / 256, 256, 0, stream>>>(hb, off, ssrc, dis, b1, A2b);
    k_gemm2_mfma<<<gblk, 256, 0, stream>>>(A2b, Wt2g, bmu, bls,
                                           out, out + (size_t)NN * 50);
}

// Round 9
// 259.537 us; speedup vs baseline: 2.6292x; 2.6292x over previous
//
#include <hip/hip_runtime.h>

#define NN 100000
#define NE 800000
#define NBLK 196    // ceil(100000/512): scan blocks AND dst-buckets (512 nodes each)
#define BCAP 6144   // bucket capacity (mean 4081, sigma ~64)
#define EPB 8192    // edges per k_part block
#define NPART ((NE + EPB - 1) / EPB)   // 98

typedef unsigned short ushort_t;
typedef unsigned int uint_t;
typedef __attribute__((ext_vector_type(8))) short short8;
typedef __attribute__((ext_vector_type(4))) float floatx4;

__device__ __forceinline__ float bf2f(ushort_t u) {
    union { unsigned int i; float f; } v; v.i = ((unsigned int)u) << 16; return v.f;
}
__device__ __forceinline__ ushort_t f2bf(float f) {
    union { float f; unsigned int i; } v; v.f = f;
    unsigned int b = v.i + 0x7FFF + ((v.i >> 16) & 1);
    return (ushort_t)(b >> 16);
}
__device__ __forceinline__ uint_t pack2(float a, float b) {
    return (uint_t)f2bf(a) | ((uint_t)f2bf(b) << 16);
}

// ---------------- partition edges into 196 dst-buckets, 2-level reservation ----------------
// record = src | (dstLocal<<17)   (src < 2^17, dstLocal < 512)
__global__ __launch_bounds__(256) void k_part(const int* __restrict__ src,
                                              const int* __restrict__ dst,
                                              int* __restrict__ bcnt,
                                              int* __restrict__ bedge) {
    __shared__ int hist[NBLK];
    __shared__ int lbase[NBLK];
    const int blk = blockIdx.x, t = threadIdx.x;
    const int e0 = blk * EPB;
    const int e1 = (e0 + EPB < NE) ? e0 + EPB : NE;

    if (t < NBLK) hist[t] = 0;
    __syncthreads();
    for (int e = e0 + t; e < e1; e += 256)
        atomicAdd(&hist[dst[e] >> 9], 1);
    __syncthreads();
    if (t < NBLK) {
        int h = hist[t];
        lbase[t] = (h > 0) ? atomicAdd(&bcnt[t], h) : 0;
    }
    __syncthreads();
    if (t < NBLK) hist[t] = lbase[t];   // reuse as cursor
    __syncthreads();
    for (int e = e0 + t; e < e1; e += 256) {
        int d = dst[e];
        int b = d >> 9;
        int pos = atomicAdd(&hist[b], 1);
        bedge[b * BCAP + pos] = src[e] | ((d & 511) << 17);
    }
}

// ---------------- per-bucket degree histogram -> deg, dis (coalesced) ----------------
__global__ __launch_bounds__(256) void k_bhist(const int* __restrict__ bcnt,
                                               const int* __restrict__ bedge,
                                               int* __restrict__ deg, float* __restrict__ dis) {
    __shared__ int hist[512];
    int b = blockIdx.x, t = threadIdx.x;
    hist[t] = 0; hist[t + 256] = 0;
    __syncthreads();
    int cnt = bcnt[b];
    const int* be = bedge + b * BCAP;
    for (int i = t; i < cnt; i += 256) {
        atomicAdd(&hist[be[i] >> 17], 1);
    }
    __syncthreads();
    #pragma unroll
    for (int q = 0; q < 2; ++q) {
        int j = t + q * 256;
        int gn = b * 512 + j;
        if (gn < NN) {
            int h = hist[j];
            deg[gn] = h;
            dis[gn] = rsqrtf((float)h + 1.0f);
        }
    }
}

// ---------------- scan: bucket totals (bcnt) -> bucket base ----------------
__global__ __launch_bounds__(256) void k_scan2(const int* __restrict__ bsum, int* __restrict__ base) {
    __shared__ int s[NBLK];
    int t = threadIdx.x;
    if (t < NBLK) s[t] = bsum[t];
    __syncthreads();
    if (t == 0) {
        int run = 0;
        for (int i = 0; i < NBLK; ++i) { int v = s[i]; s[i] = run; run += v; }
    }
    __syncthreads();
    if (t < NBLK) base[t] = s[t];
}

// ---------------- intra-bucket scan of deg -> off ----------------
__global__ __launch_bounds__(256) void k_scan3(const int* __restrict__ deg, const int* __restrict__ base,
                                               int* __restrict__ off) {
    __shared__ int s[2][512];
    int b = blockIdx.x, t = threadIdx.x;
    int g0 = b * 512;
    #pragma unroll
    for (int q = 0; q < 2; ++q) {
        int j = t + q * 256, g = g0 + j;
        s[0][j] = (g < NN) ? deg[g] : 0;
    }
    __syncthreads();
    int c = 0;
    for (int o = 1; o < 512; o <<= 1) {
        int nxt = c ^ 1;
        #pragma unroll
        for (int q = 0; q < 2; ++q) {
            int j = t + q * 256;
            s[nxt][j] = s[c][j] + ((j >= o) ? s[c][j - o] : 0);
        }
        c = nxt;
        __syncthreads();
    }
    int bb = base[b];
    #pragma unroll
    for (int q = 0; q < 2; ++q) {
        int j = t + q * 256, g = g0 + j;
        if (g <= NN) off[g] = bb + ((j > 0) ? s[c][j - 1] : 0);
    }
}

// ---------------- per-bucket CSR place: LDS cursors, contiguous slot region ----------------
__global__ __launch_bounds__(256) void k_place(const int* __restrict__ bcnt,
                                               const int* __restrict__ bedge,
                                               const int* __restrict__ off,
                                               int* __restrict__ ssrc) {
    __shared__ int lcur[512];
    int b = blockIdx.x, t = threadIdx.x;
    #pragma unroll
    for (int q = 0; q < 2; ++q) {
        int j = t + q * 256;
        int gn = b * 512 + j;
        lcur[j] = (gn < NN) ? off[gn] : 0;
    }
    __syncthreads();
    int cnt = bcnt[b];
    const int* be = bedge + b * BCAP;
    for (int i = t; i < cnt; i += 256) {
        int v = be[i];
        int s = v & 0x1FFFF;
        int dl = v >> 17;
        int pos = atomicAdd(&lcur[dl], 1);
        ssrc[pos] = s;
    }
}

// ---------------- one-shot W^T pre-pack to global (bf16 pairs) ----------------
__global__ __launch_bounds__(64) void k_packW(
    const float* __restrict__ W1,
    const float* __restrict__ Wmu, const float* __restrict__ Wls,
    uint_t* __restrict__ Wt1g, uint_t* __restrict__ Wt2g)
{
    int b = blockIdx.x;
    int mat = b / 112, n = b - mat * 112;
    int kp = threadIdx.x;
    int k0 = kp * 2, k1 = k0 + 1;
    float w0 = 0.0f, w1 = 0.0f;
    if (mat == 0) {
        if (n < 100) {
            if (k0 < 100) w0 = W1[k0 * 100 + n];
            if (k1 < 100) w1 = W1[k1 * 100 + n];
        }
        Wt1g[n * 64 + kp] = pack2(w0, w1);
    } else {
        if (n < 50) {
            if (k0 < 100) w0 = Wmu[k0 * 50 + n];
            if (k1 < 100) w1 = Wmu[k1 * 50 + n];
        } else if (n < 100) {
            if (k0 < 100) w0 = Wls[k0 * 50 + (n - 50)];
            if (k1 < 100) w1 = Wls[k1 * 50 + (n - 50)];
        }
        Wt2g[n * 64 + kp] = pack2(w0, w1);
    }
}

// ---------------- MFMA GEMM 1: H1' = bf16((X @ W1) * dis), pads zeroed ----------------
__global__ __launch_bounds__(256) void k_gemm1_mfma(
    const float* __restrict__ X, const uint_t* __restrict__ Wtg,
    const float* __restrict__ dis,
    ushort_t* __restrict__ H)
{
    __shared__ ushort_t Ws[112 * 136];   // 30.5 KB
    const int tid = threadIdx.x;
    const int row0 = blockIdx.x * 64;

    for (int idx = tid; idx < 112 * 16; idx += 256) {
        int n = idx >> 4, c = idx & 15;
        uint4 v = *(const uint4*)&Wtg[n * 64 + c * 4];
        *(uint4*)&Ws[n * 136 + c * 8] = v;
    }
    __syncthreads();

    const int wave = tid >> 6, lane = tid & 63;
    const int quad = lane >> 4, l16 = lane & 15;
    int row = row0 + wave * 16 + l16;
    if (row >= NN) row = NN - 1;
    const float* xp = X + (size_t)row * 100;

    floatx4 acc[7];
    #pragma unroll
    for (int t = 0; t < 7; ++t) acc[t] = (floatx4){0.f, 0.f, 0.f, 0.f};

    #pragma unroll
    for (int ks = 0; ks < 4; ++ks) {
        const int kb = ks * 32 + quad * 8;
        short8 af;
        if (ks < 3) {
            float4 u = *(const float4*)&xp[kb];
            float4 v = *(const float4*)&xp[kb + 4];
            af[0] = (short)f2bf(u.x); af[1] = (short)f2bf(u.y);
            af[2] = (short)f2bf(u.z); af[3] = (short)f2bf(u.w);
            af[4] = (short)f2bf(v.x); af[5] = (short)f2bf(v.y);
            af[6] = (short)f2bf(v.z); af[7] = (short)f2bf(v.w);
        } else {
            af = (short8){0, 0, 0, 0, 0, 0, 0, 0};
            if (quad == 0) {
                float4 u = *(const float4*)&xp[96];
                af[0] = (short)f2bf(u.x); af[1] = (short)f2bf(u.y);
                af[2] = (short)f2bf(u.z); af[3] = (short)f2bf(u.w);
            }
        }
        #pragma unroll
        for (int t = 0; t < 7; ++t) {
            short8 bf = *(const short8*)&Ws[(t * 16 + l16) * 136 + kb];
            acc[t] = __builtin_amdgcn_mfma_f32_16x16x32_bf16(af, bf, acc[t], 0, 0, 0);
        }
    }

    const int mbase = row0 + wave * 16 + quad * 4;
    #pragma unroll
    for (int reg = 0; reg < 4; ++reg) {
        int m = mbase + reg;
        if (m >= NN) continue;
        float dd = dis[m];
        #pragma unroll
        for (int t = 0; t < 7; ++t) {
            int n = t * 16 + l16;
            H[(size_t)m * 128 + n] = (n < 100) ? f2bf(acc[t][reg] * dd) : (ushort_t)0;
        }
        H[(size_t)m * 128 + 112 + l16] = 0;
    }
}

// ---------------- MFMA GEMM 2: out = A2 @ [Wmu|Wls] + [bmu|bls] ----------------
__global__ __launch_bounds__(256) void k_gemm2_mfma(
    const ushort_t* __restrict__ A,   // bf16, stride 128, k-padded w/ zeros
    const uint_t* __restrict__ Wtg,
    const float* __restrict__ bmu, const float* __restrict__ bls,
    float* __restrict__ outmu, float* __restrict__ outls)
{
    __shared__ ushort_t Ws[112 * 136];
    const int tid = threadIdx.x;
    const int row0 = blockIdx.x * 64;

    for (int idx = tid; idx < 112 * 16; idx += 256) {
        int n = idx >> 4, c = idx & 15;
        uint4 v = *(const uint4*)&Wtg[n * 64 + c * 4];
        *(uint4*)&Ws[n * 136 + c * 8] = v;
    }
    __syncthreads();

    const int wave = tid >> 6, lane = tid & 63;
    const int quad = lane >> 4, l16 = lane & 15;
    int arow = row0 + wave * 16 + l16;
    if (arow >= NN) arow = NN - 1;

    floatx4 acc[7];
    #pragma unroll
    for (int t = 0; t < 7; ++t) acc[t] = (floatx4){0.f, 0.f, 0.f, 0.f};

    #pragma unroll
    for (int k0 = 0; k0 < 128; k0 += 32) {
        short8 af = *(const short8*)&A[(size_t)arow * 128 + k0 + quad * 8];
        #pragma unroll
        for (int t = 0; t < 7; ++t) {
            short8 bf = *(const short8*)&Ws[(t * 16 + l16) * 136 + k0 + quad * 8];
            acc[t] = __builtin_amdgcn_mfma_f32_16x16x32_bf16(af, bf, acc[t], 0, 0, 0);
        }
    }

    const int mbase = row0 + wave * 16 + quad * 4;
    #pragma unroll
    for (int reg = 0; reg < 4; ++reg) {
        int m = mbase + reg;
        if (m >= NN) continue;
        #pragma unroll
        for (int t = 0; t < 7; ++t) {
            int n = t * 16 + l16;
            if (n < 50) {
                outmu[(size_t)m * 50 + n] = acc[t][reg] + bmu[n];
            } else if (n < 100) {
                outls[(size_t)m * 50 + (n - 50)] = acc[t][reg] + bls[n - 50];
            }
        }
    }
}

// ---------------- aggregation (gather, scale-folded, src-only CSR) ----------------
// in: H' rows (feat * dis[row]), stride 128, pads zero.
// val = dis[node] * (H'[node] + sum_e H'[src])
// PHASE 1: store bf16(relu(val + b1) * dis[node])   PHASE 2: store bf16(val)
template<int PHASE>
__global__ __launch_bounds__(256) void k_agg(
    const ushort_t* __restrict__ Hin,
    const int* __restrict__ off, const int* __restrict__ ssrc,
    const float* __restrict__ dis, const float* __restrict__ bias,
    ushort_t* __restrict__ outb)
{
    int i = blockIdx.x * 256 + threadIdx.x;
    if (i >= NN * 8) return;
    int node = i >> 3;
    int col = (i & 7) * 16;

    float a[16];
    {
        short8 u = *(const short8*)(Hin + (size_t)node * 128 + col);
        short8 v = *(const short8*)(Hin + (size_t)node * 128 + col + 8);
        #pragma unroll
        for (int j = 0; j < 8; ++j) { a[j] = bf2f((ushort_t)u[j]); a[8 + j] = bf2f((ushort_t)v[j]); }
    }

    int e0 = off[node], e1 = off[node + 1];
    int e = e0;
    for (; e + 3 < e1; e += 4) {
        int s0 = ssrc[e], s1 = ssrc[e + 1], s2 = ssrc[e + 2], s3 = ssrc[e + 3];
        short8 u0 = *(const short8*)(Hin + (size_t)s0 * 128 + col);
        short8 v0 = *(const short8*)(Hin + (size_t)s0 * 128 + col + 8);
        short8 u1 = *(const short8*)(Hin + (size_t)s1 * 128 + col);
        short8 v1 = *(const short8*)(Hin + (size_t)s1 * 128 + col + 8);
        short8 u2 = *(const short8*)(Hin + (size_t)s2 * 128 + col);
        short8 v2 = *(const short8*)(Hin + (size_t)s2 * 128 + col + 8);
        short8 u3 = *(const short8*)(Hin + (size_t)s3 * 128 + col);
        short8 v3 = *(const short8*)(Hin + (size_t)s3 * 128 + col + 8);
        #pragma unroll
        for (int j = 0; j < 8; ++j) {
            a[j]     += bf2f((ushort_t)u0[j]) + bf2f((ushort_t)u1[j])
                      + bf2f((ushort_t)u2[j]) + bf2f((ushort_t)u3[j]);
            a[8 + j] += bf2f((ushort_t)v0[j]) + bf2f((ushort_t)v1[j])
                      + bf2f((ushort_t)v2[j]) + bf2f((ushort_t)v3[j]);
        }
    }
    for (; e < e1; ++e) {
        int s0 = ssrc[e];
        short8 u0 = *(const short8*)(Hin + (size_t)s0 * 128 + col);
        short8 v0 = *(const short8*)(Hin + (size_t)s0 * 128 + col + 8);
        #pragma unroll
        for (int j = 0; j < 8; ++j) {
            a[j] += bf2f((ushort_t)u0[j]);
            a[8 + j] += bf2f((ushort_t)v0[j]);
        }
    }

    float d = dis[node];
    short8 o0, o1;
    if (PHASE == 1) {
        float b[16];
        #pragma unroll
        for (int j = 0; j < 16; ++j) {
            int cj = col + j;
            b[j] = (cj < 100) ? bias[cj] : 0.0f;
        }
        #pragma unroll
        for (int j = 0; j < 8; ++j) {
            float h0 = fmaxf(a[j] * d + b[j], 0.0f) * d;
            float h1 = fmaxf(a[8 + j] * d + b[8 + j], 0.0f) * d;
            o0[j] = (short)f2bf(h0);
            o1[j] = (short)f2bf(h1);
        }
    } else {
        #pragma unroll
        for (int j = 0; j < 8; ++j) {
            o0[j] = (short)f2bf(a[j] * d);
            o1[j] = (short)f2bf(a[8 + j] * d);
        }
    }
    *(short8*)(outb + (size_t)node * 128 + col) = o0;
    *(short8*)(outb + (size_t)node * 128 + col + 8) = o1;
}

extern "C" void kernel_launch(void* const* d_in, const int* in_sizes, int n_in,
                              void* d_out, int out_size, void* d_ws, size_t ws_size,
                              hipStream_t stream)
{
    const float* x   = (const float*)d_in[0];
    const int*   ei  = (const int*)d_in[1];
    const float* W1  = (const float*)d_in[2];
    const float* b1  = (const float*)d_in[3];
    const float* Wmu = (const float*)d_in[4];
    const float* bmu = (const float*)d_in[5];
    const float* Wls = (const float*)d_in[6];
    const float* bls = (const float*)d_in[7];
    float* out = (float*)d_out;

    const int* src = ei;
    const int* dst = ei + NE;

    // workspace layout (4B element offsets)
    int*   wsI  = (int*)d_ws;
    float* wsF  = (float*)d_ws;
    int*      deg  = wsI;                         // 100000
    int*      off  = wsI + 100000;                // 100001 -> pad 200064
    int*      base = wsI + 200384;                // 256
    float*    dis  = wsF + 200704;                // 100000
    uint_t*   Wt1g = (uint_t*)(wsI + 300704);     // 7168
    uint_t*   Wt2g = (uint_t*)(wsI + 307872);     // 7168 -> 315040
    int*      bcnt = wsI + 315040;                // 196 pad 256 -> 315296
    int*      ssrc = wsI + 315296;                // 800000 -> 1115296
    int*      bedge= wsI + 1115296;               // 196*6144 = 1204224 -> 2319520
    ushort_t* H1b  = (ushort_t*)(wsI + 2319520);  // 100000*128 bf16 -> 8719520
    ushort_t* hb   = (ushort_t*)(wsI + 8719520);  // -> 15119520
    ushort_t* A2b  = (ushort_t*)(wsI + 15119520); // -> 21519520

    hipMemsetAsync(bcnt, 0, 256 * sizeof(int), stream);
    k_part<<<NPART, 256, 0, stream>>>(src, dst, bcnt, bedge);
    k_bhist<<<NBLK, 256, 0, stream>>>(bcnt, bedge, deg, dis);
    k_scan2<<<1, 256, 0, stream>>>(bcnt, base);       // bucket totals ARE the scan-1 sums
    k_scan3<<<NBLK, 256, 0, stream>>>(deg, base, off);
    k_place<<<NBLK, 256, 0, stream>>>(bcnt, bedge, off, ssrc);
    k_packW<<<224, 64, 0, stream>>>(W1, Wmu, Wls, Wt1g, Wt2g);

    const int gblk = (NN + 63) / 64;
    // layer 1: H1' = bf16(X@W1 * dis) ; hb = bf16(relu(dis*(sum H1') + b1) * dis)
    k_gemm1_mfma<<<gblk, 256, 0, stream>>>(x, Wt1g, dis, H1b);
    k_agg<1><<<(NN * 8 + 255) / 256, 256, 0, stream>>>(H1b, off, ssrc, dis, b1, hb);
    // layer 2: A2 = bf16(dis*(sum hb)) ; out = A2@[Wmu|Wls] + bias
    k_agg<2><<<(NN * 8 + 255) / 256, 256, 0, stream>>>(hb, off, ssrc, dis, b1, A2b);
    k_gemm2_mfma<<<gblk, 256, 0, stream>>>(A2b, Wt2g, bmu, bls,
                                           out, out + (size_t)NN * 50);
}